// Round 1
// baseline (122.021 us; speedup 1.0000x reference)
//
#include <hip/hip_runtime.h>
#include <math.h>

#define N_NODES 2048
#define IN_F 128
#define OUT_F 32
#define ALPHA 0.2f
#define NEG_INF -9e15f
#define TI 4

// ---------------------------------------------------------------------------
// Kernel A: Wh1 = h @ W[:128,:], Wh2 = h @ W[128:,:]   (both [N, 32])
// 8 nodes per block, 256 threads: thread (r = t>>5, f = t&31) computes both
// Wh1[i0+r][f] and Wh2[i0+r][f]. W reads are wave-dedup'd (same addr across r).
// ---------------------------------------------------------------------------
__global__ __launch_bounds__(256) void precompute_wh(
    const float* __restrict__ h, const float* __restrict__ W,
    float* __restrict__ Wh1, float* __restrict__ Wh2)
{
    __shared__ float h_s[8][IN_F];
    const int t = threadIdx.x;
    const int i0 = blockIdx.x * 8;

    // load 8 h-rows (1024 floats) coalesced
    #pragma unroll
    for (int j = 0; j < 4; ++j) {
        int e = t + 256 * j;
        h_s[e >> 7][e & 127] = h[i0 * IN_F + e];
    }
    __syncthreads();

    const int f = t & 31;
    const int r = t >> 5;
    float acc1 = 0.f, acc2 = 0.f;
    #pragma unroll 4
    for (int c = 0; c < IN_F; ++c) {
        float hv = h_s[r][c];
        acc1 += hv * W[c * OUT_F + f];
        acc2 += hv * W[(IN_F + c) * OUT_F + f];
    }
    Wh1[(i0 + r) * OUT_F + f] = acc1;
    Wh2[(i0 + r) * OUT_F + f] = acc2;
}

// ---------------------------------------------------------------------------
// Kernel B: per block, TI=4 destination rows i0..i0+3.
// Phase 1: scores for all k (Wh2[k] loaded once as float4s, reused for 4 i's)
// Phase 2: masked softmax (max reduce, exp, sum reduce)
// Phase 3: h_prime[i,:] = sum_k p[i,k] * Wh1[k,:]  (Wh1[k] load reused x4)
// ---------------------------------------------------------------------------
__global__ __launch_bounds__(256) void gat_row(
    const float* __restrict__ Wh1, const float* __restrict__ Wh2,
    const int* __restrict__ adj, const float* __restrict__ a,
    float* __restrict__ out)
{
    __shared__ float s_s[TI][N_NODES];     // scores, then p = exp(s - M)
    __shared__ float w1s[TI][OUT_F];       // Wh1 rows for the 4 i's
    __shared__ float a_s[OUT_F];
    __shared__ float wred[TI][4];          // per-wave reduction scratch
    __shared__ float Ms[TI], Ls[TI];
    __shared__ float part[8][TI][OUT_F];   // phase-3 partials

    const int t = threadIdx.x;
    const int i0 = blockIdx.x * TI;

    if (t < TI * OUT_F) w1s[t >> 5][t & 31] = Wh1[i0 * OUT_F + t];
    if (t < OUT_F) a_s[t] = a[t];
    __syncthreads();

    float areg[OUT_F];
    #pragma unroll
    for (int f = 0; f < OUT_F; ++f) areg[f] = a_s[f];

    // ---------------- Phase 1: scores ----------------
    float m0 = NEG_INF, m1 = NEG_INF, m2 = NEG_INF, m3 = NEG_INF;
    for (int kc = 0; kc < 8; ++kc) {
        const int k = t + 256 * kc;
        const float4* w2v = (const float4*)(Wh2 + k * OUT_F);
        float acc0 = 0.f, acc1 = 0.f, acc2 = 0.f, acc3 = 0.f;
        #pragma unroll
        for (int j = 0; j < 8; ++j) {
            float4 q = w2v[j];
            #pragma unroll
            for (int e = 0; e < 4; ++e) {
                const int f = 4 * j + e;
                const float wf = (e == 0) ? q.x : (e == 1) ? q.y : (e == 2) ? q.z : q.w;
                const float af = areg[f];
                float x;
                x = w1s[0][f] + wf; acc0 += af * fmaxf(x, ALPHA * x);
                x = w1s[1][f] + wf; acc1 += af * fmaxf(x, ALPHA * x);
                x = w1s[2][f] + wf; acc2 += af * fmaxf(x, ALPHA * x);
                x = w1s[3][f] + wf; acc3 += af * fmaxf(x, ALPHA * x);
            }
        }
        const int base = i0 * N_NODES + k;
        float s0 = (adj[base + 0 * N_NODES] > 0) ? acc0 : NEG_INF;
        float s1 = (adj[base + 1 * N_NODES] > 0) ? acc1 : NEG_INF;
        float s2 = (adj[base + 2 * N_NODES] > 0) ? acc2 : NEG_INF;
        float s3 = (adj[base + 3 * N_NODES] > 0) ? acc3 : NEG_INF;
        s_s[0][k] = s0; m0 = fmaxf(m0, s0);
        s_s[1][k] = s1; m1 = fmaxf(m1, s1);
        s_s[2][k] = s2; m2 = fmaxf(m2, s2);
        s_s[3][k] = s3; m3 = fmaxf(m3, s3);
    }

    // block max-reduce (shuffle within wave64, then LDS across 4 waves)
    const int lane = t & 63, wid = t >> 6;
    #pragma unroll
    for (int off = 32; off > 0; off >>= 1) {
        m0 = fmaxf(m0, __shfl_down(m0, off, 64));
        m1 = fmaxf(m1, __shfl_down(m1, off, 64));
        m2 = fmaxf(m2, __shfl_down(m2, off, 64));
        m3 = fmaxf(m3, __shfl_down(m3, off, 64));
    }
    if (lane == 0) { wred[0][wid] = m0; wred[1][wid] = m1; wred[2][wid] = m2; wred[3][wid] = m3; }
    __syncthreads();
    if (t < TI) {
        Ms[t] = fmaxf(fmaxf(wred[t][0], wred[t][1]), fmaxf(wred[t][2], wred[t][3]));
    }
    __syncthreads();

    // ---------------- Phase 2: exp + sum ----------------
    const float M0 = Ms[0], M1 = Ms[1], M2 = Ms[2], M3 = Ms[3];
    float l0 = 0.f, l1 = 0.f, l2 = 0.f, l3 = 0.f;
    for (int kc = 0; kc < 8; ++kc) {
        const int k = t + 256 * kc;
        float p0 = __expf(s_s[0][k] - M0); s_s[0][k] = p0; l0 += p0;
        float p1 = __expf(s_s[1][k] - M1); s_s[1][k] = p1; l1 += p1;
        float p2 = __expf(s_s[2][k] - M2); s_s[2][k] = p2; l2 += p2;
        float p3 = __expf(s_s[3][k] - M3); s_s[3][k] = p3; l3 += p3;
    }
    #pragma unroll
    for (int off = 32; off > 0; off >>= 1) {
        l0 += __shfl_down(l0, off, 64);
        l1 += __shfl_down(l1, off, 64);
        l2 += __shfl_down(l2, off, 64);
        l3 += __shfl_down(l3, off, 64);
    }
    __syncthreads();   // wred reuse: make sure Ms reads done
    if (lane == 0) { wred[0][wid] = l0; wred[1][wid] = l1; wred[2][wid] = l2; wred[3][wid] = l3; }
    __syncthreads();
    if (t < TI) {
        Ls[t] = wred[t][0] + wred[t][1] + wred[t][2] + wred[t][3];
    }
    __syncthreads();

    // ---------------- Phase 3: aggregate ----------------
    const int f = t & 31, c = t >> 5;   // c in 0..7, 256-k chunk each
    float acc0 = 0.f, acc1 = 0.f, acc2 = 0.f, acc3 = 0.f;
    const int k0 = c * 256;
    #pragma unroll 4
    for (int kk = 0; kk < 256; ++kk) {
        const int k = k0 + kk;
        const float wv = Wh1[k * OUT_F + f];
        acc0 += s_s[0][k] * wv;
        acc1 += s_s[1][k] * wv;
        acc2 += s_s[2][k] * wv;
        acc3 += s_s[3][k] * wv;
    }
    part[c][0][f] = acc0;
    part[c][1][f] = acc1;
    part[c][2][f] = acc2;
    part[c][3][f] = acc3;
    __syncthreads();

    if (t < TI * OUT_F) {
        const int ii = t >> 5, ff = t & 31;
        float sum = 0.f;
        #pragma unroll
        for (int c2 = 0; c2 < 8; ++c2) sum += part[c2][ii][ff];
        const float val = sum / Ls[ii];
        out[(i0 + ii) * OUT_F + ff] = (val > 0.f) ? val : (__expf(val) - 1.f);
    }
}

extern "C" void kernel_launch(void* const* d_in, const int* in_sizes, int n_in,
                              void* d_out, int out_size, void* d_ws, size_t ws_size,
                              hipStream_t stream) {
    const float* h   = (const float*)d_in[0];
    const int*   adj = (const int*)d_in[1];
    const float* W   = (const float*)d_in[2];
    const float* a   = (const float*)d_in[3];
    float* out = (float*)d_out;

    float* Wh1 = (float*)d_ws;
    float* Wh2 = Wh1 + N_NODES * OUT_F;

    precompute_wh<<<N_NODES / 8, 256, 0, stream>>>(h, W, Wh1, Wh2);
    gat_row<<<N_NODES / TI, 256, 0, stream>>>(Wh1, Wh2, adj, a, out);
}